// Round 1
// baseline (17890.482 us; speedup 1.0000x reference)
//
#include <hip/hip_runtime.h>
#include <hip/hip_cooperative_groups.h>

// ============================================================================
// 2-layer LSTM (B=256,T=512,IN=128,H=512) + per-step linear (OUT=128).
// Architecture: persistent cooperative kernel, 256 blocks (1/CU) x 512 thr.
//  - 8 batch-groups x 32 wgs; group g owns batches [g*32, g*32+32).
//  - wg w owns h-dims [w*16, w*16+16) of both layers (64 gate rows each).
//  - All in-loop weights live in VGPRs as fp16 MFMA B-fragments (~104 VGPR).
//  - Per step: phaseA gates1 = Whh1@h1 + Wih1@x_t ; phaseB gates2 = Wih2@h1 +
//    Whh2@h2.  K split 4-ways across wave-pairs, partials reduced via LDS.
//  - h exchanged through global fp16 buffers + per-group atomic barrier
//    (agent-scope fences for cross-XCD safety; placement heuristic keeps a
//    group on one XCD: g = blockIdx & 7 under round-robin block->XCD).
//  - h2 history -> workspace; separate MFMA kernel does out = h2 @ Wlin^T + b.
// ============================================================================

#define Bsz 256
#define Tsz 512
#define INsz 128
#define Hsz 512
#define OUTsz 128

typedef _Float16 half8 __attribute__((ext_vector_type(8)));
typedef float f32x16 __attribute__((ext_vector_type(16)));
typedef float f32x4 __attribute__((ext_vector_type(4)));
typedef unsigned int u32x4 __attribute__((ext_vector_type(4)));

#define ROWP 520          // padded halves per 512-wide LDS row (bank spread, 16B aligned)
#define XROWP 136         // padded halves per 128-wide x row
// dynamic LDS layout (bytes)
#define H1S_B 0           // [32][520] fp16
#define H2S_B 33280       // [32][520] fp16
#define XS_B  66560       // [32][136] fp16
#define GEX_B 75264       // [2 tiles][4 kq][32 col][36 row] f32
#define LDS1_SIZE 112128
#define LDS2_SIZE 133120  // out_gemm: As[64][520] + Bs[64][520] fp16

__device__ __forceinline__ float sigm(float v)   { return 1.0f / (1.0f + __expf(-v)); }
__device__ __forceinline__ float tanh_f(float v) { return 2.0f / (1.0f + __expf(-2.0f * v)) - 1.0f; }

__device__ __forceinline__ half8 load_w8(const float* src) {
  f32x4 a = *(const f32x4*)src;
  f32x4 b = *(const f32x4*)(src + 4);
  half8 v;
  v[0] = (_Float16)a[0]; v[1] = (_Float16)a[1]; v[2] = (_Float16)a[2]; v[3] = (_Float16)a[3];
  v[4] = (_Float16)b[0]; v[5] = (_Float16)b[1]; v[6] = (_Float16)b[2]; v[7] = (_Float16)b[3];
  return v;
}

// group barrier: monotonic counter, arrive+spin by thread 0, agent fences for
// cross-XCD visibility of the ordinary h-buffer stores/loads.
__device__ __forceinline__ void group_barrier(unsigned int* cnt, unsigned int target) {
  __syncthreads();                       // all wg stores issued+drained (vmcnt before s_barrier)
  if (threadIdx.x == 0) {
    __threadfence();                     // release: writeback L2 so other XCDs can see h slices
    __hip_atomic_fetch_add(cnt, 1u, __ATOMIC_RELAXED, __HIP_MEMORY_SCOPE_AGENT);
    while (__hip_atomic_load(cnt, __ATOMIC_RELAXED, __HIP_MEMORY_SCOPE_AGENT) < target) {
      __builtin_amdgcn_s_sleep(4);
    }
    __threadfence();                     // acquire: invalidate L1/L2 before restage reads
  }
  __syncthreads();
}

__device__ __forceinline__ void dump_acc(float* gex, const f32x16& acc, int tq, int kq, int nloc, int ktop) {
  #pragma unroll
  for (int r4 = 0; r4 < 4; ++r4) {
    f32x4 v;
    v[0] = acc[r4*4+0]; v[1] = acc[r4*4+1]; v[2] = acc[r4*4+2]; v[3] = acc[r4*4+3];
    // C/D layout 32x32: col=lane&31, row=(reg&3)+8*(reg>>2)+4*(lane>>5); store col-major [col][row]
    *(f32x4*)(gex + ((tq*4 + kq)*32 + nloc)*36 + r4*8 + ktop*4) = v;
  }
}

__device__ __forceinline__ void epilogue_gates(const float* gex, int eb, int ed,
                                               float bi, float bf, float bg, float bo,
                                               float& c, float& hout) {
  float gi = bi, gf = bf, gg = bg, go = bo;
  #pragma unroll
  for (int q = 0; q < 4; ++q) {             // sum 4 K-quarter partials
    gi += gex[(q*32 + ed)*36 + eb];         // tile0 cols 0..15 = i
    gf += gex[(q*32 + ed + 16)*36 + eb];    // tile0 cols 16..31 = f
    gg += gex[((4+q)*32 + ed)*36 + eb];     // tile1 cols 0..15 = g
    go += gex[((4+q)*32 + ed + 16)*36 + eb];// tile1 cols 16..31 = o
  }
  float ii = sigm(gi), ff = sigm(gf), ta = tanh_f(gg), oo = sigm(go);
  c = ff * c + ii * ta;
  hout = oo * tanh_f(c);
}

__global__ void __launch_bounds__(512, 2) lstm_seq(
    const float* __restrict__ x,
    const float* __restrict__ Wih1, const float* __restrict__ Whh1,
    const float* __restrict__ bih1, const float* __restrict__ bhh1,
    const float* __restrict__ Wih2, const float* __restrict__ Whh2,
    const float* __restrict__ bih2, const float* __restrict__ bhh2,
    unsigned int* cnt_base,
    _Float16* __restrict__ hbuf1, _Float16* __restrict__ hbuf2,
    _Float16* __restrict__ h2hist)
{
  extern __shared__ char lds[];
  _Float16* h1s = (_Float16*)(lds + H1S_B);
  _Float16* h2s = (_Float16*)(lds + H2S_B);
  _Float16* xs  = (_Float16*)(lds + XS_B);
  float*    gex = (float*)(lds + GEX_B);

  const int tid  = threadIdx.x;
  const int lane = tid & 63;
  const int wv   = tid >> 6;     // 0..7
  const int tq   = wv & 1;       // which 32-col gate tile (0: i|f, 1: g|o)
  const int kq   = wv >> 1;      // K quarter 0..3
  const int g    = blockIdx.x & 7;   // group (XCD-local heuristic)
  const int w    = blockIdx.x >> 3;  // member 0..31

  unsigned int* cnt = cnt_base + g * 64;   // one 256B-separated counter per group

  // lane's output column within its tile -> weight row
  const int nloc  = lane & 31;
  const int ktop  = lane >> 5;                 // k-octet select in frags
  const int gtype = tq * 2 + (nloc >> 4);      // 0:i 1:f 2:g 3:o
  const int wdim  = w * 16 + (nloc & 15);
  const int grow  = gtype * 512 + wdim;        // row in the 2048-row weight mats

  // ---- persistent weight fragments (B-operand layout: lane holds W[grow][k..k+8]) ----
  half8 wA[10], wB[16];
  #pragma unroll
  for (int s = 0; s < 8; ++s)
    wA[s] = load_w8(Whh1 + (size_t)grow * Hsz + (kq*8 + s)*16 + ktop*8);
  #pragma unroll
  for (int s = 0; s < 2; ++s)
    wA[8+s] = load_w8(Wih1 + (size_t)grow * INsz + kq*32 + s*16 + ktop*8);
  #pragma unroll
  for (int s = 0; s < 8; ++s)
    wB[s] = load_w8(Wih2 + (size_t)grow * Hsz + (kq*8 + s)*16 + ktop*8);
  #pragma unroll
  for (int s = 0; s < 8; ++s)
    wB[8+s] = load_w8(Whh2 + (size_t)grow * Hsz + (kq*8 + s)*16 + ktop*8);

  // ---- epilogue ownership: thread = (batch eb, dim ed) ----
  const int eb = tid & 31;
  const int ed = tid >> 5;           // 0..15
  const int edim = w * 16 + ed;
  float bi1 = bih1[0*512+edim] + bhh1[0*512+edim];
  float bf1 = bih1[1*512+edim] + bhh1[1*512+edim];
  float bg1 = bih1[2*512+edim] + bhh1[2*512+edim];
  float bo1 = bih1[3*512+edim] + bhh1[3*512+edim];
  float bi2 = bih2[0*512+edim] + bhh2[0*512+edim];
  float bf2 = bih2[1*512+edim] + bhh2[1*512+edim];
  float bg2 = bih2[2*512+edim] + bhh2[2*512+edim];
  float bo2 = bih2[3*512+edim] + bhh2[3*512+edim];
  float c1 = 0.0f, c2 = 0.0f;

  // zero initial h state in LDS
  const int stg_m = tid >> 4, stg_ch = tid & 15;
  {
    u32x4 z = {0, 0, 0, 0};
    #pragma unroll
    for (int i = 0; i < 4; ++i) {
      *(u32x4*)(h1s + stg_m*ROWP + stg_ch*32 + i*8) = z;
      *(u32x4*)(h2s + stg_m*ROWP + stg_ch*32 + i*8) = z;
    }
  }
  __syncthreads();

  unsigned int bar_no = 0;

  for (int t = 0; t < Tsz; ++t) {
    // ---- stage x_t (fp32 -> fp16) ----
    {
      const float* src = x + ((size_t)(g*32 + stg_m) * Tsz + t) * INsz + stg_ch*8;
      *(half8*)(xs + stg_m*XROWP + stg_ch*8) = load_w8(src);
    }
    __syncthreads();

    // ---- phase A: gates1 = Whh1 @ h1(t-1) + Wih1 @ x_t ----
    f32x16 acc;
    #pragma unroll
    for (int i = 0; i < 16; ++i) acc[i] = 0.0f;
    #pragma unroll
    for (int s = 0; s < 8; ++s) {
      half8 a = *(const half8*)(h1s + nloc*ROWP + (kq*8 + s)*16 + ktop*8);
      acc = __builtin_amdgcn_mfma_f32_32x32x16_f16(a, wA[s], acc, 0, 0, 0);
    }
    #pragma unroll
    for (int s = 0; s < 2; ++s) {
      half8 a = *(const half8*)(xs + nloc*XROWP + kq*32 + s*16 + ktop*8);
      acc = __builtin_amdgcn_mfma_f32_32x32x16_f16(a, wA[8+s], acc, 0, 0, 0);
    }
    dump_acc(gex, acc, tq, kq, nloc, ktop);
    __syncthreads();
    {
      float h;
      epilogue_gates(gex, eb, ed, bi1, bf1, bg1, bo1, c1, h);
      hbuf1[(g*32 + eb) * Hsz + edim] = (_Float16)h;
    }
    bar_no += 32;
    group_barrier(cnt, bar_no);
    // restage full h1(t)
    {
      const _Float16* src = hbuf1 + (g*32 + stg_m) * Hsz + stg_ch*32;
      #pragma unroll
      for (int i = 0; i < 4; ++i)
        *(u32x4*)(h1s + stg_m*ROWP + stg_ch*32 + i*8) = *(const u32x4*)(src + i*8);
    }
    __syncthreads();

    // ---- phase B: gates2 = Wih2 @ h1(t) + Whh2 @ h2(t-1) ----
    #pragma unroll
    for (int i = 0; i < 16; ++i) acc[i] = 0.0f;
    #pragma unroll
    for (int s = 0; s < 8; ++s) {
      half8 a = *(const half8*)(h1s + nloc*ROWP + (kq*8 + s)*16 + ktop*8);
      acc = __builtin_amdgcn_mfma_f32_32x32x16_f16(a, wB[s], acc, 0, 0, 0);
    }
    #pragma unroll
    for (int s = 0; s < 8; ++s) {
      half8 a = *(const half8*)(h2s + nloc*ROWP + (kq*8 + s)*16 + ktop*8);
      acc = __builtin_amdgcn_mfma_f32_32x32x16_f16(a, wB[8+s], acc, 0, 0, 0);
    }
    dump_acc(gex, acc, tq, kq, nloc, ktop);
    __syncthreads();
    {
      float h;
      epilogue_gates(gex, eb, ed, bi2, bf2, bg2, bo2, c2, h);
      _Float16 hh = (_Float16)h;
      hbuf2[(g*32 + eb) * Hsz + edim] = hh;
      h2hist[((size_t)(g*32 + eb) * Tsz + t) * Hsz + edim] = hh;
    }
    bar_no += 32;
    group_barrier(cnt, bar_no);
    // restage full h2(t)
    {
      const _Float16* src = hbuf2 + (g*32 + stg_m) * Hsz + stg_ch*32;
      #pragma unroll
      for (int i = 0; i < 4; ++i)
        *(u32x4*)(h2s + stg_m*ROWP + stg_ch*32 + i*8) = *(const u32x4*)(src + i*8);
    }
    __syncthreads();
  }
}

// ======================= final linear: out = H2 @ Wlin^T + b =================
__global__ void __launch_bounds__(256) out_gemm(
    const _Float16* __restrict__ h2hist, const float* __restrict__ Wlin,
    const float* __restrict__ blin, float* __restrict__ out)
{
  extern __shared__ char lds[];
  _Float16* As = (_Float16*)lds;              // [64][520]
  _Float16* Bs = (_Float16*)(lds + 66560);    // [64][520]
  const int tid = threadIdx.x;
  const int bt0 = blockIdx.x * 64;
  const int n0  = blockIdx.y * 64;

  {
    const int r = tid >> 2, k0 = (tid & 3) * 128;
    const u32x4* src = (const u32x4*)(h2hist + (size_t)(bt0 + r) * Hsz + k0);
    #pragma unroll
    for (int i = 0; i < 16; ++i)
      *(u32x4*)(As + r*ROWP + k0 + i*8) = src[i];
  }
  {
    const int n = tid >> 2, k0 = (tid & 3) * 128;
    const float* src = Wlin + (size_t)(n0 + n) * Hsz + k0;
    #pragma unroll
    for (int i = 0; i < 16; ++i)
      *(half8*)(Bs + n*ROWP + k0 + i*8) = load_w8(src + i*8);
  }
  __syncthreads();

  const int lane = tid & 63;
  const int wvid = tid >> 6;           // M-tile 0..3
  const int mrow = wvid*16 + (lane & 15);
  const int kt   = lane >> 4;          // 0..3
  f32x4 acc[4];
  #pragma unroll
  for (int nt = 0; nt < 4; ++nt) { acc[nt][0]=0; acc[nt][1]=0; acc[nt][2]=0; acc[nt][3]=0; }

  #pragma unroll
  for (int ks = 0; ks < 16; ++ks) {
    half8 a = *(const half8*)(As + mrow*ROWP + ks*32 + kt*8);
    #pragma unroll
    for (int nt = 0; nt < 4; ++nt) {
      half8 b = *(const half8*)(Bs + (nt*16 + (lane & 15))*ROWP + ks*32 + kt*8);
      acc[nt] = __builtin_amdgcn_mfma_f32_16x16x32_f16(a, b, acc[nt], 0, 0, 0);
    }
  }
  #pragma unroll
  for (int nt = 0; nt < 4; ++nt) {
    const int n = n0 + nt*16 + (lane & 15);
    const float bb = blin[n];
    #pragma unroll
    for (int r = 0; r < 4; ++r) {
      const int row = bt0 + wvid*16 + (lane >> 4)*4 + r;  // C/D: col=lane&15, row=quad*4+reg
      out[(size_t)row * OUTsz + n] = acc[nt][r] + bb;
    }
  }
}

extern "C" void kernel_launch(void* const* d_in, const int* in_sizes, int n_in,
                              void* d_out, int out_size, void* d_ws, size_t ws_size,
                              hipStream_t stream) {
  const float* x    = (const float*)d_in[0];
  // d_in[1] = future (always 0) — ignored
  const float* Wih1 = (const float*)d_in[2];
  const float* Whh1 = (const float*)d_in[3];
  const float* bih1 = (const float*)d_in[4];
  const float* bhh1 = (const float*)d_in[5];
  const float* Wih2 = (const float*)d_in[6];
  const float* Whh2 = (const float*)d_in[7];
  const float* bih2 = (const float*)d_in[8];
  const float* bhh2 = (const float*)d_in[9];
  const float* Wlin = (const float*)d_in[10];
  const float* blin = (const float*)d_in[11];
  float* out = (float*)d_out;

  char* ws = (char*)d_ws;
  unsigned int* cnt = (unsigned int*)ws;                  // 8 x 256B counters
  _Float16* hbuf1  = (_Float16*)(ws + 4096);              // 256 KB
  _Float16* hbuf2  = (_Float16*)(ws + 4096 + 262144);     // 256 KB
  _Float16* h2hist = (_Float16*)(ws + 1048576);           // 128 MB

  hipMemsetAsync(ws, 0, 4096, stream);                    // zero barrier counters every call

  hipFuncSetAttribute((const void*)lstm_seq, hipFuncAttributeMaxDynamicSharedMemorySize, LDS1_SIZE);
  hipFuncSetAttribute((const void*)out_gemm, hipFuncAttributeMaxDynamicSharedMemorySize, LDS2_SIZE);

  void* args[] = { (void*)&x, (void*)&Wih1, (void*)&Whh1, (void*)&bih1, (void*)&bhh1,
                   (void*)&Wih2, (void*)&Whh2, (void*)&bih2, (void*)&bhh2,
                   (void*)&cnt, (void*)&hbuf1, (void*)&hbuf2, (void*)&h2hist };
  hipLaunchCooperativeKernel((const void*)lstm_seq, dim3(256), dim3(512), args,
                             (unsigned int)LDS1_SIZE, stream);

  out_gemm<<<dim3(2048, 2), dim3(256), LDS2_SIZE, stream>>>(h2hist, Wlin, blin, out);
}

// Round 4
// 7188.927 us; speedup vs baseline: 2.4886x; 2.4886x over previous
//
#include <hip/hip_runtime.h>

// ============================================================================
// 2-layer LSTM (B=256,T=512,IN=128,H=512) + per-step linear (OUT=128).
// Persistent cooperative kernel, 256 blocks (1/CU) x 512 thr.
//  - 8 batch-groups x 32 wgs; group g owns batches [g*32,g*32+32).
//  - wg w owns h-dims [w*16,w*16+16) of both layers (64 gate rows each).
//  - Weights persist in unified VGPR/AGPR file as fp16 MFMA B-frags (104 regs).
//  - Layers software-pipelined: iteration i computes h1(i) AND h2(i-1) from
//    state exchanged at the previous barrier -> ONE barrier per step.
//  - R3 post-mortem: R2/R3 failed DETERMINISTICALLY (identical absmax) from a
//    partial-block indexing bug (dump at wv=kq*2+tq vs epilogue reading
//    tq*4+kq), NOT from sync semantics. Fixed: dump block = tq*4+kq (R1's
//    proven layout).
//  - Barrier: release-arrive (1 buffer_wbl2 sc1), relaxed spin, one acquire
//    (1 buffer_inv sc1) at exit. 1+1 cache ops/step vs R1's 4+4.
// ============================================================================

#define Bsz 256
#define Tsz 512
#define INsz 128
#define Hsz 512
#define OUTsz 128

typedef _Float16 half8 __attribute__((ext_vector_type(8)));
typedef float f32x16 __attribute__((ext_vector_type(16)));
typedef float f32x4 __attribute__((ext_vector_type(4)));
typedef unsigned int u32x4 __attribute__((ext_vector_type(4)));

#define ROWP 520          // halves per 512-wide LDS row (16B-aligned stride)
#define XROWP 136         // halves per 128-wide x row
// dynamic LDS layout (bytes)
#define H1S_B 0           // [32][520] fp16
#define H2S_B 33280       // [32][520] fp16
#define XS_B  66560       // [32][136] fp16
#define GEXA_B 75264      // [8 blocks][32 col][36 row] f32 (layer-1 partials)
#define GEXB_B 112128     // [8 blocks][32 col][36 row] f32 (layer-2 partials)
#define LDS1_SIZE 148992
#define LDS2_SIZE 133120  // out_gemm: As[64][520] + Bs[64][520] fp16

__device__ __forceinline__ float sigm(float v)   { return 1.0f / (1.0f + __expf(-v)); }
__device__ __forceinline__ float tanh_f(float v) { return 2.0f / (1.0f + __expf(-2.0f * v)) - 1.0f; }

__device__ __forceinline__ half8 load_w8(const float* src) {
  f32x4 a = *(const f32x4*)src;
  f32x4 b = *(const f32x4*)(src + 4);
  half8 v;
  v[0] = (_Float16)a[0]; v[1] = (_Float16)a[1]; v[2] = (_Float16)a[2]; v[3] = (_Float16)a[3];
  v[4] = (_Float16)b[0]; v[5] = (_Float16)b[1]; v[6] = (_Float16)b[2]; v[7] = (_Float16)b[3];
  return v;
}

// blk MUST be tq*4+kq: epilogue reads blocks [0..3]=tile0(i|f), [4..7]=tile1(g|o)
__device__ __forceinline__ void dump_acc(float* gex, const f32x16& acc, int blk, int nloc, int ktop) {
  #pragma unroll
  for (int r4 = 0; r4 < 4; ++r4) {
    f32x4 v;
    v[0] = acc[r4*4+0]; v[1] = acc[r4*4+1]; v[2] = acc[r4*4+2]; v[3] = acc[r4*4+3];
    // C/D layout 32x32: col=lane&31, row=(reg&3)+8*(reg>>2)+4*(lane>>5); store [col][row]
    *(f32x4*)(gex + (blk*32 + nloc)*36 + r4*8 + ktop*4) = v;
  }
}

__device__ __forceinline__ void epilogue_gates(const float* gex, int eb, int ed,
                                               float bi, float bf, float bg, float bo,
                                               float& c, float& hout) {
  float gi = bi, gf = bf, gg = bg, go = bo;
  #pragma unroll
  for (int q = 0; q < 4; ++q) {             // sum 4 K-quarter partials
    gi += gex[(q*32 + ed)*36 + eb];         // blocks 0..3, cols 0..15  = i
    gf += gex[(q*32 + ed + 16)*36 + eb];    // blocks 0..3, cols 16..31 = f
    gg += gex[((4+q)*32 + ed)*36 + eb];     // blocks 4..7, cols 0..15  = g
    go += gex[((4+q)*32 + ed + 16)*36 + eb];// blocks 4..7, cols 16..31 = o
  }
  float ii = sigm(gi), ff = sigm(gf), ta = tanh_f(gg), oo = sigm(go);
  c = ff * c + ii * ta;
  hout = oo * tanh_f(c);
}

__device__ __forceinline__ unsigned h_bits(float h) {
  union { _Float16 f; unsigned short u; } cv;
  cv.f = (_Float16)h;
  return (unsigned)cv.u;
}

__global__ void __launch_bounds__(512, 2) lstm_seq(
    const float* __restrict__ x,
    const float* __restrict__ Wih1, const float* __restrict__ Whh1,
    const float* __restrict__ bih1, const float* __restrict__ bhh1,
    const float* __restrict__ Wih2, const float* __restrict__ Whh2,
    const float* __restrict__ bih2, const float* __restrict__ bhh2,
    unsigned int* cnt_base,
    unsigned int* __restrict__ hbuf1, unsigned int* __restrict__ hbuf2, // fp16 pairs
    unsigned int* __restrict__ h2hist)                                  // fp16 pairs
{
  extern __shared__ char lds[];
  _Float16* h1s = (_Float16*)(lds + H1S_B);
  _Float16* h2s = (_Float16*)(lds + H2S_B);
  _Float16* xs  = (_Float16*)(lds + XS_B);
  float*    gexA = (float*)(lds + GEXA_B);
  float*    gexB = (float*)(lds + GEXB_B);

  const int tid  = threadIdx.x;
  const int lane = tid & 63;
  const int wv   = tid >> 6;     // 0..7
  const int tq   = wv & 1;       // gate tile (0: i|f, 1: g|o)
  const int kq   = wv >> 1;      // K quarter 0..3
  const int blk  = tq * 4 + kq;  // partial-block index expected by epilogue
  const int g    = blockIdx.x & 7;   // batch group (XCD-local heuristic)
  const int w    = blockIdx.x >> 3;  // member 0..31

  unsigned int* cnt = cnt_base + g * 64;

  const int nloc  = lane & 31;
  const int ktop  = lane >> 5;
  const int gtype = tq * 2 + (nloc >> 4);      // 0:i 1:f 2:g 3:o
  const int wdim  = w * 16 + (nloc & 15);
  const int grow  = gtype * 512 + wdim;

  // ---- persistent weight fragments (B-operand: lane holds W[grow][k..k+8]) ----
  half8 wA[10], wB[16];
  #pragma unroll
  for (int s = 0; s < 8; ++s)
    wA[s] = load_w8(Whh1 + (size_t)grow * Hsz + (kq*8 + s)*16 + ktop*8);
  #pragma unroll
  for (int s = 0; s < 2; ++s)
    wA[8+s] = load_w8(Wih1 + (size_t)grow * INsz + kq*32 + s*16 + ktop*8);
  #pragma unroll
  for (int s = 0; s < 8; ++s)
    wB[s] = load_w8(Wih2 + (size_t)grow * Hsz + (kq*8 + s)*16 + ktop*8);
  #pragma unroll
  for (int s = 0; s < 8; ++s)
    wB[8+s] = load_w8(Whh2 + (size_t)grow * Hsz + (kq*8 + s)*16 + ktop*8);

  // ---- epilogue ownership: ed = dim-local (adjacent lanes), eb = batch ----
  const int ed = tid & 15;
  const int eb = tid >> 4;           // 0..31
  const int edim = w * 16 + ed;
  float bi1 = bih1[0*512+edim] + bhh1[0*512+edim];
  float bf1 = bih1[1*512+edim] + bhh1[1*512+edim];
  float bg1 = bih1[2*512+edim] + bhh1[2*512+edim];
  float bo1 = bih1[3*512+edim] + bhh1[3*512+edim];
  float bi2 = bih2[0*512+edim] + bhh2[0*512+edim];
  float bf2 = bih2[1*512+edim] + bhh2[1*512+edim];
  float bg2 = bih2[2*512+edim] + bhh2[2*512+edim];
  float bo2 = bih2[3*512+edim] + bhh2[3*512+edim];
  float c1 = 0.0f, c2 = 0.0f;

  const int stg_m = tid >> 4, stg_ch = tid & 15;
  {
    u32x4 z = {0, 0, 0, 0};
    #pragma unroll
    for (int i2 = 0; i2 < 4; ++i2) {
      *(u32x4*)(h1s + stg_m*ROWP + stg_ch*32 + i2*8) = z;
      *(u32x4*)(h2s + stg_m*ROWP + stg_ch*32 + i2*8) = z;
    }
  }
  __syncthreads();

  // iteration i: layer-1 computes h1(i) (i<T), layer-2 computes h2(i-1) (i>0)
  for (int i = 0; i <= Tsz; ++i) {
    const bool doA = (i < Tsz);
    const bool doB = (i > 0);

    if (doA) {  // stage x_i (fp32 -> fp16)
      const float* src = x + ((size_t)(g*32 + stg_m) * Tsz + i) * INsz + stg_ch*8;
      *(half8*)(xs + stg_m*XROWP + stg_ch*8) = load_w8(src);
    }
    __syncthreads();   // xs + restaged h1s/h2s ready

    if (doA) {  // gates1 = Whh1 @ h1(i-1) + Wih1 @ x_i
      f32x16 acc;
      #pragma unroll
      for (int k = 0; k < 16; ++k) acc[k] = 0.0f;
      #pragma unroll
      for (int s = 0; s < 8; ++s) {
        half8 a = *(const half8*)(h1s + nloc*ROWP + (kq*8 + s)*16 + ktop*8);
        acc = __builtin_amdgcn_mfma_f32_32x32x16_f16(a, wA[s], acc, 0, 0, 0);
      }
      #pragma unroll
      for (int s = 0; s < 2; ++s) {
        half8 a = *(const half8*)(xs + nloc*XROWP + kq*32 + s*16 + ktop*8);
        acc = __builtin_amdgcn_mfma_f32_32x32x16_f16(a, wA[8+s], acc, 0, 0, 0);
      }
      dump_acc(gexA, acc, blk, nloc, ktop);
    }
    if (doB) {  // gates2 = Wih2 @ h1(i-1) + Whh2 @ h2(i-2)
      f32x16 acc;
      #pragma unroll
      for (int k = 0; k < 16; ++k) acc[k] = 0.0f;
      #pragma unroll
      for (int s = 0; s < 8; ++s) {
        half8 a = *(const half8*)(h1s + nloc*ROWP + (kq*8 + s)*16 + ktop*8);
        acc = __builtin_amdgcn_mfma_f32_32x32x16_f16(a, wB[s], acc, 0, 0, 0);
      }
      #pragma unroll
      for (int s = 0; s < 8; ++s) {
        half8 a = *(const half8*)(h2s + nloc*ROWP + (kq*8 + s)*16 + ktop*8);
        acc = __builtin_amdgcn_mfma_f32_32x32x16_f16(a, wB[s+8], acc, 0, 0, 0);
      }
      dump_acc(gexB, acc, blk, nloc, ktop);
    }
    __syncthreads();   // partials visible

    // ---- epilogues: pack 2 fp16 per dword ----
    if (doA) {
      float h;
      epilogue_gates(gexA, eb, ed, bi1, bf1, bg1, bo1, c1, h);
      unsigned lo = h_bits(h);
      unsigned hi = __shfl_down(lo, 1, 64);
      if (!(tid & 1))
        hbuf1[((g*32 + eb)*Hsz + w*16 + ed) >> 1] = lo | (hi << 16);
    }
    if (doB) {
      float h;
      epilogue_gates(gexB, eb, ed, bi2, bf2, bg2, bo2, c2, h);
      unsigned lo = h_bits(h);
      unsigned hi = __shfl_down(lo, 1, 64);
      if (!(tid & 1)) {
        unsigned v = lo | (hi << 16);
        hbuf2[((g*32 + eb)*Hsz + w*16 + ed) >> 1] = v;
        // nontemporal: keep L2 clean so the release-wbl2 below is cheap
        __builtin_nontemporal_store(v,
            h2hist + ((((size_t)(g*32 + eb)*Tsz + (i-1))*Hsz + w*16 + ed) >> 1));
      }
    }
    if (i == Tsz) break;   // last h2 stored; no further exchange needed

    // ---- group barrier: release-arrive, relaxed spin, one acquire at exit ----
    __syncthreads();       // all waves drained their stores (vmcnt 0) into L2
    if (tid == 0) {
      // RELEASE: dirty h-lines in this XCD's L2 pushed to coherence point.
      __hip_atomic_fetch_add(cnt, 1u, __ATOMIC_RELEASE, __HIP_MEMORY_SCOPE_AGENT);
      const unsigned target = (unsigned)(i + 1) * 32u;
      while (__hip_atomic_load(cnt, __ATOMIC_RELAXED, __HIP_MEMORY_SCOPE_AGENT) < target)
        __builtin_amdgcn_s_sleep(1);
      // ACQUIRE once: drop stale local cache lines before restage.
      (void)__hip_atomic_load(cnt, __ATOMIC_ACQUIRE, __HIP_MEMORY_SCOPE_AGENT);
    }
    __syncthreads();

    // ---- restage h1(i), h2(i-1) ----
    {
      const int row = tid >> 4, c0 = tid & 15;
      const unsigned* s1 = hbuf1 + (g*32 + row) * (Hsz/2);
      unsigned* d1 = (unsigned*)(h1s + row*ROWP);
      #pragma unroll
      for (int j = 0; j < 16; ++j)
        d1[j*16 + c0] = __hip_atomic_load(s1 + j*16 + c0, __ATOMIC_RELAXED, __HIP_MEMORY_SCOPE_AGENT);
      if (i > 0) {
        const unsigned* s2 = hbuf2 + (g*32 + row) * (Hsz/2);
        unsigned* d2 = (unsigned*)(h2s + row*ROWP);
        #pragma unroll
        for (int j = 0; j < 16; ++j)
          d2[j*16 + c0] = __hip_atomic_load(s2 + j*16 + c0, __ATOMIC_RELAXED, __HIP_MEMORY_SCOPE_AGENT);
      }
    }
    // no sync here: next-iteration top __syncthreads covers LDS write->read
  }
}

// ======================= final linear: out = H2 @ Wlin^T + b =================
__global__ void __launch_bounds__(256) out_gemm(
    const _Float16* __restrict__ h2hist, const float* __restrict__ Wlin,
    const float* __restrict__ blin, float* __restrict__ out)
{
  extern __shared__ char lds[];
  _Float16* As = (_Float16*)lds;              // [64][520]
  _Float16* Bs = (_Float16*)(lds + 66560);    // [64][520]
  const int tid = threadIdx.x;
  const int bt0 = blockIdx.x * 64;
  const int n0  = blockIdx.y * 64;

  {
    const int r = tid >> 2, k0 = (tid & 3) * 128;
    const u32x4* src = (const u32x4*)(h2hist + (size_t)(bt0 + r) * Hsz + k0);
    #pragma unroll
    for (int i = 0; i < 16; ++i)
      *(u32x4*)(As + r*ROWP + k0 + i*8) = src[i];
  }
  {
    const int n = tid >> 2, k0 = (tid & 3) * 128;
    const float* src = Wlin + (size_t)(n0 + n) * Hsz + k0;
    #pragma unroll
    for (int i = 0; i < 16; ++i)
      *(half8*)(Bs + n*ROWP + k0 + i*8) = load_w8(src + i*8);
  }
  __syncthreads();

  const int lane = tid & 63;
  const int wvid = tid >> 6;           // M-tile 0..3
  const int mrow = wvid*16 + (lane & 15);
  const int kt   = lane >> 4;          // 0..3
  f32x4 acc[4];
  #pragma unroll
  for (int nt = 0; nt < 4; ++nt) { acc[nt][0]=0; acc[nt][1]=0; acc[nt][2]=0; acc[nt][3]=0; }

  #pragma unroll
  for (int ks = 0; ks < 16; ++ks) {
    half8 a = *(const half8*)(As + mrow*ROWP + ks*32 + kt*8);
    #pragma unroll
    for (int nt = 0; nt < 4; ++nt) {
      half8 b = *(const half8*)(Bs + (nt*16 + (lane & 15))*ROWP + ks*32 + kt*8);
      acc[nt] = __builtin_amdgcn_mfma_f32_16x16x32_f16(a, b, acc[nt], 0, 0, 0);
    }
  }
  #pragma unroll
  for (int nt = 0; nt < 4; ++nt) {
    const int n = n0 + nt*16 + (lane & 15);
    const float bb = blin[n];
    #pragma unroll
    for (int r = 0; r < 4; ++r) {
      const int row = bt0 + wvid*16 + (lane >> 4)*4 + r;  // C/D: col=lane&15, row=quad*4+reg
      out[(size_t)row * OUTsz + n] = acc[nt][r] + bb;
    }
  }
}

extern "C" void kernel_launch(void* const* d_in, const int* in_sizes, int n_in,
                              void* d_out, int out_size, void* d_ws, size_t ws_size,
                              hipStream_t stream) {
  const float* x    = (const float*)d_in[0];
  const float* Wih1 = (const float*)d_in[2];
  const float* Whh1 = (const float*)d_in[3];
  const float* bih1 = (const float*)d_in[4];
  const float* bhh1 = (const float*)d_in[5];
  const float* Wih2 = (const float*)d_in[6];
  const float* Whh2 = (const float*)d_in[7];
  const float* bih2 = (const float*)d_in[8];
  const float* bhh2 = (const float*)d_in[9];
  const float* Wlin = (const float*)d_in[10];
  const float* blin = (const float*)d_in[11];
  float* out = (float*)d_out;

  char* ws = (char*)d_ws;
  unsigned int* cnt    = (unsigned int*)ws;               // 8 x 256B counters
  unsigned int* hbuf1  = (unsigned int*)(ws + 4096);      // 256 KB (fp16 pairs)
  unsigned int* hbuf2  = (unsigned int*)(ws + 4096 + 262144);
  unsigned int* h2hist = (unsigned int*)(ws + 1048576);   // 128 MB (fp16 pairs)

  hipMemsetAsync(ws, 0, 4096, stream);                    // zero barrier counters

  hipFuncSetAttribute((const void*)lstm_seq, hipFuncAttributeMaxDynamicSharedMemorySize, LDS1_SIZE);
  hipFuncSetAttribute((const void*)out_gemm, hipFuncAttributeMaxDynamicSharedMemorySize, LDS2_SIZE);

  void* args[] = { (void*)&x, (void*)&Wih1, (void*)&Whh1, (void*)&bih1, (void*)&bhh1,
                   (void*)&Wih2, (void*)&Whh2, (void*)&bih2, (void*)&bhh2,
                   (void*)&cnt, (void*)&hbuf1, (void*)&hbuf2, (void*)&h2hist };
  hipLaunchCooperativeKernel((const void*)lstm_seq, dim3(256), dim3(512), args,
                             (unsigned int)LDS1_SIZE, stream);

  out_gemm<<<dim3(2048, 2), dim3(256), LDS2_SIZE, stream>>>((const _Float16*)h2hist, Wlin, blin, out);
}

// Round 5
// 5282.970 us; speedup vs baseline: 3.3864x; 1.3608x over previous
//
#include <hip/hip_runtime.h>

// ============================================================================
// 2-layer LSTM (B=256,T=512,IN=128,H=512) + per-step linear (OUT=128).
// Persistent cooperative kernel, 256 blocks (1/CU) x 512 thr.
//  - 8 batch-groups x 32 wgs; group g owns batches [g*32,g*32+32).
//  - wg w owns h-dims [w*16,w*16+16) of both layers (64 gate rows each).
//  - Weights persist in unified VGPR/AGPR file as fp16 MFMA B-frags (104 regs).
//  - Layers software-pipelined: iteration i computes h1(i) AND h2(i-1) from
//    state exchanged at the previous barrier -> ONE barrier per step.
//  - R5: fence-free exchange (R2 semantics, now with R4's dump_acc bugfix).
//    Evidence: R2/R3 failed with BIT-IDENTICAL absmax under different sync
//    semantics -> failure was the indexing bug, not sync. So: h-stores are
//    agent-scope relaxed atomics (sc1 write-through to coherence point;
//    __syncthreads' vmcnt(0) is the release), arrive = relaxed fetch_add,
//    restage = sc1 relaxed atomic loads (bypass stale L1/L2). ZERO
//    buffer_wbl2/buffer_inv per step (R4 paid ~6.6us/step for its 1+1).
// ============================================================================

#define Bsz 256
#define Tsz 512
#define INsz 128
#define Hsz 512
#define OUTsz 128

typedef _Float16 half8 __attribute__((ext_vector_type(8)));
typedef float f32x16 __attribute__((ext_vector_type(16)));
typedef float f32x4 __attribute__((ext_vector_type(4)));
typedef unsigned int u32x4 __attribute__((ext_vector_type(4)));

#define ROWP 520          // halves per 512-wide LDS row (16B-aligned stride)
#define XROWP 136         // halves per 128-wide x row
// dynamic LDS layout (bytes)
#define H1S_B 0           // [32][520] fp16
#define H2S_B 33280       // [32][520] fp16
#define XS_B  66560       // [32][136] fp16
#define GEXA_B 75264      // [8 blocks][32 col][36 row] f32 (layer-1 partials)
#define GEXB_B 112128     // [8 blocks][32 col][36 row] f32 (layer-2 partials)
#define LDS1_SIZE 148992
#define LDS2_SIZE 133120  // out_gemm: As[64][520] + Bs[64][520] fp16

__device__ __forceinline__ float sigm(float v)   { return 1.0f / (1.0f + __expf(-v)); }
__device__ __forceinline__ float tanh_f(float v) { return 2.0f / (1.0f + __expf(-2.0f * v)) - 1.0f; }

__device__ __forceinline__ half8 load_w8(const float* src) {
  f32x4 a = *(const f32x4*)src;
  f32x4 b = *(const f32x4*)(src + 4);
  half8 v;
  v[0] = (_Float16)a[0]; v[1] = (_Float16)a[1]; v[2] = (_Float16)a[2]; v[3] = (_Float16)a[3];
  v[4] = (_Float16)b[0]; v[5] = (_Float16)b[1]; v[6] = (_Float16)b[2]; v[7] = (_Float16)b[3];
  return v;
}

// blk MUST be tq*4+kq: epilogue reads blocks [0..3]=tile0(i|f), [4..7]=tile1(g|o)
__device__ __forceinline__ void dump_acc(float* gex, const f32x16& acc, int blk, int nloc, int ktop) {
  #pragma unroll
  for (int r4 = 0; r4 < 4; ++r4) {
    f32x4 v;
    v[0] = acc[r4*4+0]; v[1] = acc[r4*4+1]; v[2] = acc[r4*4+2]; v[3] = acc[r4*4+3];
    // C/D layout 32x32: col=lane&31, row=(reg&3)+8*(reg>>2)+4*(lane>>5); store [col][row]
    *(f32x4*)(gex + (blk*32 + nloc)*36 + r4*8 + ktop*4) = v;
  }
}

__device__ __forceinline__ void epilogue_gates(const float* gex, int eb, int ed,
                                               float bi, float bf, float bg, float bo,
                                               float& c, float& hout) {
  float gi = bi, gf = bf, gg = bg, go = bo;
  #pragma unroll
  for (int q = 0; q < 4; ++q) {             // sum 4 K-quarter partials
    gi += gex[(q*32 + ed)*36 + eb];         // blocks 0..3, cols 0..15  = i
    gf += gex[(q*32 + ed + 16)*36 + eb];    // blocks 0..3, cols 16..31 = f
    gg += gex[((4+q)*32 + ed)*36 + eb];     // blocks 4..7, cols 0..15  = g
    go += gex[((4+q)*32 + ed + 16)*36 + eb];// blocks 4..7, cols 16..31 = o
  }
  float ii = sigm(gi), ff = sigm(gf), ta = tanh_f(gg), oo = sigm(go);
  c = ff * c + ii * ta;
  hout = oo * tanh_f(c);
}

__device__ __forceinline__ unsigned h_bits(float h) {
  union { _Float16 f; unsigned short u; } cv;
  cv.f = (_Float16)h;
  return (unsigned)cv.u;
}

__global__ void __launch_bounds__(512, 2) lstm_seq(
    const float* __restrict__ x,
    const float* __restrict__ Wih1, const float* __restrict__ Whh1,
    const float* __restrict__ bih1, const float* __restrict__ bhh1,
    const float* __restrict__ Wih2, const float* __restrict__ Whh2,
    const float* __restrict__ bih2, const float* __restrict__ bhh2,
    unsigned int* cnt_base,
    unsigned int* __restrict__ hbuf1, unsigned int* __restrict__ hbuf2, // fp16 pairs
    unsigned int* __restrict__ h2hist)                                  // fp16 pairs
{
  extern __shared__ char lds[];
  _Float16* h1s = (_Float16*)(lds + H1S_B);
  _Float16* h2s = (_Float16*)(lds + H2S_B);
  _Float16* xs  = (_Float16*)(lds + XS_B);
  float*    gexA = (float*)(lds + GEXA_B);
  float*    gexB = (float*)(lds + GEXB_B);

  const int tid  = threadIdx.x;
  const int lane = tid & 63;
  const int wv   = tid >> 6;     // 0..7
  const int tq   = wv & 1;       // gate tile (0: i|f, 1: g|o)
  const int kq   = wv >> 1;      // K quarter 0..3
  const int blk  = tq * 4 + kq;  // partial-block index expected by epilogue
  const int g    = blockIdx.x & 7;   // batch group (XCD-local heuristic)
  const int w    = blockIdx.x >> 3;  // member 0..31

  unsigned int* cnt = cnt_base + g * 64;

  const int nloc  = lane & 31;
  const int ktop  = lane >> 5;
  const int gtype = tq * 2 + (nloc >> 4);      // 0:i 1:f 2:g 3:o
  const int wdim  = w * 16 + (nloc & 15);
  const int grow  = gtype * 512 + wdim;

  // ---- persistent weight fragments (B-operand: lane holds W[grow][k..k+8]) ----
  half8 wA[10], wB[16];
  #pragma unroll
  for (int s = 0; s < 8; ++s)
    wA[s] = load_w8(Whh1 + (size_t)grow * Hsz + (kq*8 + s)*16 + ktop*8);
  #pragma unroll
  for (int s = 0; s < 2; ++s)
    wA[8+s] = load_w8(Wih1 + (size_t)grow * INsz + kq*32 + s*16 + ktop*8);
  #pragma unroll
  for (int s = 0; s < 8; ++s)
    wB[s] = load_w8(Wih2 + (size_t)grow * Hsz + (kq*8 + s)*16 + ktop*8);
  #pragma unroll
  for (int s = 0; s < 8; ++s)
    wB[8+s] = load_w8(Whh2 + (size_t)grow * Hsz + (kq*8 + s)*16 + ktop*8);

  // ---- epilogue ownership: ed = dim-local (adjacent lanes), eb = batch ----
  const int ed = tid & 15;
  const int eb = tid >> 4;           // 0..31
  const int edim = w * 16 + ed;
  float bi1 = bih1[0*512+edim] + bhh1[0*512+edim];
  float bf1 = bih1[1*512+edim] + bhh1[1*512+edim];
  float bg1 = bih1[2*512+edim] + bhh1[2*512+edim];
  float bo1 = bih1[3*512+edim] + bhh1[3*512+edim];
  float bi2 = bih2[0*512+edim] + bhh2[0*512+edim];
  float bf2 = bih2[1*512+edim] + bhh2[1*512+edim];
  float bg2 = bih2[2*512+edim] + bhh2[2*512+edim];
  float bo2 = bih2[3*512+edim] + bhh2[3*512+edim];
  float c1 = 0.0f, c2 = 0.0f;

  const int stg_m = tid >> 4, stg_ch = tid & 15;
  {
    u32x4 z = {0, 0, 0, 0};
    #pragma unroll
    for (int i2 = 0; i2 < 4; ++i2) {
      *(u32x4*)(h1s + stg_m*ROWP + stg_ch*32 + i2*8) = z;
      *(u32x4*)(h2s + stg_m*ROWP + stg_ch*32 + i2*8) = z;
    }
  }
  __syncthreads();

  // iteration i: layer-1 computes h1(i) (i<T), layer-2 computes h2(i-1) (i>0)
  for (int i = 0; i <= Tsz; ++i) {
    const bool doA = (i < Tsz);
    const bool doB = (i > 0);

    if (doA) {  // stage x_i (fp32 -> fp16)
      const float* src = x + ((size_t)(g*32 + stg_m) * Tsz + i) * INsz + stg_ch*8;
      *(half8*)(xs + stg_m*XROWP + stg_ch*8) = load_w8(src);
    }
    __syncthreads();   // xs + restaged h1s/h2s ready

    if (doA) {  // gates1 = Whh1 @ h1(i-1) + Wih1 @ x_i
      f32x16 acc;
      #pragma unroll
      for (int k = 0; k < 16; ++k) acc[k] = 0.0f;
      #pragma unroll
      for (int s = 0; s < 8; ++s) {
        half8 a = *(const half8*)(h1s + nloc*ROWP + (kq*8 + s)*16 + ktop*8);
        acc = __builtin_amdgcn_mfma_f32_32x32x16_f16(a, wA[s], acc, 0, 0, 0);
      }
      #pragma unroll
      for (int s = 0; s < 2; ++s) {
        half8 a = *(const half8*)(xs + nloc*XROWP + kq*32 + s*16 + ktop*8);
        acc = __builtin_amdgcn_mfma_f32_32x32x16_f16(a, wA[8+s], acc, 0, 0, 0);
      }
      dump_acc(gexA, acc, blk, nloc, ktop);
    }
    if (doB) {  // gates2 = Wih2 @ h1(i-1) + Whh2 @ h2(i-2)
      f32x16 acc;
      #pragma unroll
      for (int k = 0; k < 16; ++k) acc[k] = 0.0f;
      #pragma unroll
      for (int s = 0; s < 8; ++s) {
        half8 a = *(const half8*)(h1s + nloc*ROWP + (kq*8 + s)*16 + ktop*8);
        acc = __builtin_amdgcn_mfma_f32_32x32x16_f16(a, wB[s], acc, 0, 0, 0);
      }
      #pragma unroll
      for (int s = 0; s < 8; ++s) {
        half8 a = *(const half8*)(h2s + nloc*ROWP + (kq*8 + s)*16 + ktop*8);
        acc = __builtin_amdgcn_mfma_f32_32x32x16_f16(a, wB[s+8], acc, 0, 0, 0);
      }
      dump_acc(gexB, acc, blk, nloc, ktop);
    }
    __syncthreads();   // partials visible

    // ---- epilogues: pack 2 fp16 per dword, sc1 write-through stores ----
    if (doA) {
      float h;
      epilogue_gates(gexA, eb, ed, bi1, bf1, bg1, bo1, c1, h);
      unsigned lo = h_bits(h);
      unsigned hi = __shfl_down(lo, 1, 64);
      if (!(tid & 1))
        __hip_atomic_store(hbuf1 + (((g*32 + eb)*Hsz + w*16 + ed) >> 1),
                           lo | (hi << 16), __ATOMIC_RELAXED, __HIP_MEMORY_SCOPE_AGENT);
    }
    if (doB) {
      float h;
      epilogue_gates(gexB, eb, ed, bi2, bf2, bg2, bo2, c2, h);
      unsigned lo = h_bits(h);
      unsigned hi = __shfl_down(lo, 1, 64);
      if (!(tid & 1)) {
        unsigned v = lo | (hi << 16);
        __hip_atomic_store(hbuf2 + (((g*32 + eb)*Hsz + w*16 + ed) >> 1),
                           v, __ATOMIC_RELAXED, __HIP_MEMORY_SCOPE_AGENT);
        // nontemporal plain store; visibility to out_gemm via kernel boundary
        __builtin_nontemporal_store(v,
            h2hist + ((((size_t)(g*32 + eb)*Tsz + (i-1))*Hsz + w*16 + ed) >> 1));
      }
    }
    if (i == Tsz) break;   // last h2 stored; no further exchange needed

    // ---- fence-free group barrier ----
    __syncthreads();   // vmcnt(0): every wave's sc1 stores acked at coherence
                       // point before any wave proceeds => release semantics
    if (tid == 0) {
      __hip_atomic_fetch_add(cnt, 1u, __ATOMIC_RELAXED, __HIP_MEMORY_SCOPE_AGENT);
      const unsigned target = (unsigned)(i + 1) * 32u;
      while (__hip_atomic_load(cnt, __ATOMIC_RELAXED, __HIP_MEMORY_SCOPE_AGENT) < target)
        __builtin_amdgcn_s_sleep(1);
    }
    __syncthreads();

    // ---- restage h1(i), h2(i-1): sc1 loads bypass stale L1/L2 ----
    {
      const int row = tid >> 4, c0 = tid & 15;
      const unsigned* s1 = hbuf1 + (g*32 + row) * (Hsz/2);
      unsigned* d1 = (unsigned*)(h1s + row*ROWP);
      #pragma unroll
      for (int j = 0; j < 16; ++j)
        d1[j*16 + c0] = __hip_atomic_load(s1 + j*16 + c0, __ATOMIC_RELAXED, __HIP_MEMORY_SCOPE_AGENT);
      if (i > 0) {
        const unsigned* s2 = hbuf2 + (g*32 + row) * (Hsz/2);
        unsigned* d2 = (unsigned*)(h2s + row*ROWP);
        #pragma unroll
        for (int j = 0; j < 16; ++j)
          d2[j*16 + c0] = __hip_atomic_load(s2 + j*16 + c0, __ATOMIC_RELAXED, __HIP_MEMORY_SCOPE_AGENT);
      }
    }
    // no sync here: next-iteration top __syncthreads covers LDS write->read
  }
}

// ======================= final linear: out = H2 @ Wlin^T + b =================
__global__ void __launch_bounds__(256) out_gemm(
    const _Float16* __restrict__ h2hist, const float* __restrict__ Wlin,
    const float* __restrict__ blin, float* __restrict__ out)
{
  extern __shared__ char lds[];
  _Float16* As = (_Float16*)lds;              // [64][520]
  _Float16* Bs = (_Float16*)(lds + 66560);    // [64][520]
  const int tid = threadIdx.x;
  const int bt0 = blockIdx.x * 64;
  const int n0  = blockIdx.y * 64;

  {
    const int r = tid >> 2, k0 = (tid & 3) * 128;
    const u32x4* src = (const u32x4*)(h2hist + (size_t)(bt0 + r) * Hsz + k0);
    #pragma unroll
    for (int i = 0; i < 16; ++i)
      *(u32x4*)(As + r*ROWP + k0 + i*8) = src[i];
  }
  {
    const int n = tid >> 2, k0 = (tid & 3) * 128;
    const float* src = Wlin + (size_t)(n0 + n) * Hsz + k0;
    #pragma unroll
    for (int i = 0; i < 16; ++i)
      *(half8*)(Bs + n*ROWP + k0 + i*8) = load_w8(src + i*8);
  }
  __syncthreads();

  const int lane = tid & 63;
  const int wvid = tid >> 6;           // M-tile 0..3
  const int mrow = wvid*16 + (lane & 15);
  const int kt   = lane >> 4;          // 0..3
  f32x4 acc[4];
  #pragma unroll
  for (int nt = 0; nt < 4; ++nt) { acc[nt][0]=0; acc[nt][1]=0; acc[nt][2]=0; acc[nt][3]=0; }

  #pragma unroll
  for (int ks = 0; ks < 16; ++ks) {
    half8 a = *(const half8*)(As + mrow*ROWP + ks*32 + kt*8);
    #pragma unroll
    for (int nt = 0; nt < 4; ++nt) {
      half8 b = *(const half8*)(Bs + (nt*16 + (lane & 15))*ROWP + ks*32 + kt*8);
      acc[nt] = __builtin_amdgcn_mfma_f32_16x16x32_f16(a, b, acc[nt], 0, 0, 0);
    }
  }
  #pragma unroll
  for (int nt = 0; nt < 4; ++nt) {
    const int n = n0 + nt*16 + (lane & 15);
    const float bb = blin[n];
    #pragma unroll
    for (int r = 0; r < 4; ++r) {
      const int row = bt0 + wvid*16 + (lane >> 4)*4 + r;  // C/D: col=lane&15, row=quad*4+reg
      out[(size_t)row * OUTsz + n] = acc[nt][r] + bb;
    }
  }
}

extern "C" void kernel_launch(void* const* d_in, const int* in_sizes, int n_in,
                              void* d_out, int out_size, void* d_ws, size_t ws_size,
                              hipStream_t stream) {
  const float* x    = (const float*)d_in[0];
  const float* Wih1 = (const float*)d_in[2];
  const float* Whh1 = (const float*)d_in[3];
  const float* bih1 = (const float*)d_in[4];
  const float* bhh1 = (const float*)d_in[5];
  const float* Wih2 = (const float*)d_in[6];
  const float* Whh2 = (const float*)d_in[7];
  const float* bih2 = (const float*)d_in[8];
  const float* bhh2 = (const float*)d_in[9];
  const float* Wlin = (const float*)d_in[10];
  const float* blin = (const float*)d_in[11];
  float* out = (float*)d_out;

  char* ws = (char*)d_ws;
  unsigned int* cnt    = (unsigned int*)ws;               // 8 x 256B counters
  unsigned int* hbuf1  = (unsigned int*)(ws + 4096);      // 256 KB (fp16 pairs)
  unsigned int* hbuf2  = (unsigned int*)(ws + 4096 + 262144);
  unsigned int* h2hist = (unsigned int*)(ws + 1048576);   // 128 MB (fp16 pairs)

  hipMemsetAsync(ws, 0, 4096, stream);                    // zero barrier counters

  hipFuncSetAttribute((const void*)lstm_seq, hipFuncAttributeMaxDynamicSharedMemorySize, LDS1_SIZE);
  hipFuncSetAttribute((const void*)out_gemm, hipFuncAttributeMaxDynamicSharedMemorySize, LDS2_SIZE);

  void* args[] = { (void*)&x, (void*)&Wih1, (void*)&Whh1, (void*)&bih1, (void*)&bhh1,
                   (void*)&Wih2, (void*)&Whh2, (void*)&bih2, (void*)&bhh2,
                   (void*)&cnt, (void*)&hbuf1, (void*)&hbuf2, (void*)&h2hist };
  hipLaunchCooperativeKernel((const void*)lstm_seq, dim3(256), dim3(512), args,
                             (unsigned int)LDS1_SIZE, stream);

  out_gemm<<<dim3(2048, 2), dim3(256), LDS2_SIZE, stream>>>((const _Float16*)h2hist, Wlin, blin, out);
}